// Round 3
// baseline (163.482 us; speedup 1.0000x reference)
//
#include <hip/hip_runtime.h>
#include <hip/hip_bf16.h>

#define B_    2
#define S_    2048
#define DIN   1024
#define EMB   1024
#define NH    16
#define HD    64
#define N3    3072
#define MROWS 4096   // B_*S_
#define KVB   64
#define QBLK  128
#define NT    (S_ / KVB)   // 32 kv tiles

typedef short bf16x8 __attribute__((ext_vector_type(8)));
typedef float f32x4  __attribute__((ext_vector_type(4)));
typedef unsigned short u16;
typedef u16 u16x8 __attribute__((ext_vector_type(8)));
typedef u16 u16x4 __attribute__((ext_vector_type(4)));
typedef unsigned int u32;

__device__ __forceinline__ u16 f2bf(float f) {
  union { float f; unsigned u; } x; x.f = f;
  unsigned r = x.u + 0x7fffu + ((x.u >> 16) & 1u);
  return (u16)(r >> 16);
}

__device__ __forceinline__ u32 cvtpk(float lo, float hi) {
  u32 r;
  asm("v_cvt_pk_bf16_f32 %0, %1, %2" : "=v"(r) : "v"(lo), "v"(hi));
  return r;
}

__device__ __forceinline__ void gload16(const void* g, void* l) {
  __builtin_amdgcn_global_load_lds(
      (const __attribute__((address_space(1))) unsigned int*)g,
      (__attribute__((address_space(3))) unsigned int*)l, 16, 0, 0);
}

__global__ void cast4(const float* __restrict__ in, u16* __restrict__ out, int n4) {
  const int i = blockIdx.x * 256 + threadIdx.x;
  if (i < n4) {
    const float4 v = ((const float4*)in)[i];
    u16x4 o;
    o[0] = f2bf(v.x); o[1] = f2bf(v.y); o[2] = f2bf(v.z); o[3] = f2bf(v.w);
    ((u16x4*)out)[i] = o;
  }
}

// C[m,n] = sum_k A[m,k] * W[n,k] + bias[n]; A:[M][K] bf16, W:[N][K] bf16.
// EPI==0: scatter Q,K -> [B,H,S,d] bf16 (Q scaled by 0.125*log2e), V -> V^T [B,H,d,S].
// EPI==1: f32 out.
template<int EPI>
__global__ __launch_bounds__(256)
void gemm_bt(const u16* __restrict__ A, const u16* __restrict__ W,
             const float* __restrict__ bias, float* __restrict__ Cf,
             u16* __restrict__ Qb, u16* __restrict__ Kb, u16* __restrict__ VbT,
             int M, int N, int K) {
  __shared__ u16 Als[128 * 32];
  __shared__ u16 Bls[128 * 32];
  const int tid  = threadIdx.x;
  const int wave = tid >> 6, lane = tid & 63;
  const int lhi  = lane >> 4, llo = lane & 15;
  const int wr   = wave >> 1, wc = wave & 1;
  const int m0   = blockIdx.y * 128, n0 = blockIdx.x * 128;

  const f32x4 fzero = {0.f, 0.f, 0.f, 0.f};
  f32x4 acc[4][4];
#pragma unroll
  for (int m = 0; m < 4; ++m)
#pragma unroll
    for (int n = 0; n < 4; ++n) acc[m][n] = fzero;

  for (int k0 = 0; k0 < K; k0 += 32) {
#pragma unroll
    for (int i = 0; i < 2; ++i) {
      const int e   = (tid + i * 256) * 8;   // element index in [128][32] tile
      const int row = e >> 5, col = e & 31;
      gload16(A + (size_t)(m0 + row) * K + k0 + col, (char*)Als + wave * 1024 + i * 4096);
      gload16(W + (size_t)(n0 + row) * K + k0 + col, (char*)Bls + wave * 1024 + i * 4096);
    }
    __syncthreads();
    bf16x8 af[4], bfr[4];
#pragma unroll
    for (int m = 0; m < 4; ++m) af[m]  = *(const bf16x8*)&Als[(wr * 64 + m * 16 + llo) * 32 + lhi * 8];
#pragma unroll
    for (int n = 0; n < 4; ++n) bfr[n] = *(const bf16x8*)&Bls[(wc * 64 + n * 16 + llo) * 32 + lhi * 8];
#pragma unroll
    for (int m = 0; m < 4; ++m)
#pragma unroll
      for (int n = 0; n < 4; ++n)
        acc[m][n] = __builtin_amdgcn_mfma_f32_16x16x32_bf16(af[m], bfr[n], acc[m][n], 0, 0, 0);
    __syncthreads();
  }

#pragma unroll
  for (int n = 0; n < 4; ++n) {
    const int colb = n0 + wc * 64 + n * 16;  // 16-aligned; never crosses a 64-col section
    const int gcol = colb + llo;
    const float bv = bias[gcol];
    if (EPI == 0) {
      const int h   = colb / 192;
      const int rr  = colb - h * 192;
      const int sec = rr >> 6;               // 0:Q 1:K 2:V
      const int d   = (rr & 63) + llo;
#pragma unroll
      for (int m = 0; m < 4; ++m) {
        const int rowb = m0 + wr * 64 + m * 16 + lhi * 4;
        const int b = rowb >> 11, s0 = rowb & 2047;
        if (sec == 2) {
          u16x4 vv;
#pragma unroll
          for (int r = 0; r < 4; ++r) vv[r] = f2bf(acc[m][n][r] + bv);
          *(u16x4*)&VbT[((size_t)(b * NH + h) * HD + d) * S_ + s0] = vv;
        } else {
          u16* dst = (sec == 0) ? Qb : Kb;
          const float scl = (sec == 0) ? 0.18033688f : 1.0f;  // 0.125*log2(e) for Q
#pragma unroll
          for (int r = 0; r < 4; ++r)
            dst[(((size_t)(b * NH + h) * S_ + s0 + r) << 6) + d] = f2bf((acc[m][n][r] + bv) * scl);
        }
      }
    } else {
#pragma unroll
      for (int m = 0; m < 4; ++m) {
        const int rowb = m0 + wr * 64 + m * 16 + lhi * 4;
#pragma unroll
        for (int r = 0; r < 4; ++r)
          Cf[(size_t)(rowb + r) * N + gcol] = acc[m][n][r] + bv;
      }
    }
  }
}

// Flash attention fwd: grid (S/QBLK, B*NH), 512 threads = 8 waves, 16 q-rows/wave.
// Quad-buffered K/V LDS, prefetch depth 3, counted vmcnt (never 0 in main loop),
// raw s_barrier. Swapped QK^T; P in registers via cvt_pk + shfl redistribution.
__global__ __launch_bounds__(512)
void attn_fwd(const u16* __restrict__ Qb, const u16* __restrict__ Kb,
              const u16* __restrict__ VbT, u16* __restrict__ Obf) {
  __shared__ __align__(16) u16 Kls[4][KVB * HD];   // 4 x 8KB
  __shared__ __align__(16) u16 Vls[4][HD * KVB];   // 4 x 8KB
  const int tid  = threadIdx.x;
  const int wave = tid >> 6, lane = tid & 63;
  const int lhi  = lane >> 4, llo = lane & 15;
  const int bh   = blockIdx.y;
  const int q0   = blockIdx.x * QBLK;
  const size_t base  = (size_t)bh * S_ * HD;   // Q, K
  const size_t basev = (size_t)bh * HD * S_;   // V^T

  // Q fragments: rows q0 + wave*16 + llo
  bf16x8 qf[2];
#pragma unroll
  for (int kk = 0; kk < 2; ++kk)
    qf[kk] = *(const bf16x8*)&Qb[base + (size_t)(q0 + wave * 16 + llo) * HD + kk * 32 + lhi * 8];

  // staging: 512 threads x 16B = one 8KB tile; LDS dest linear (slot=tid),
  // global source inverse-swizzled so swizzled reads return plain (row,slot)
  const int srow  = tid >> 3;                      // 0..63
  const int xslot = (tid & 7) ^ (srow & 7);
  const u16* kSrc = Kb  + base  + (size_t)srow * HD + xslot * 8;
  const u16* vSrc = VbT + basev + (size_t)srow * S_ + xslot * 8;
  const int ldsOff = wave * 1024;

  // swizzled read byte-offsets for row llo (+j*2048), slots kk*4+lhi
  const int ro  = llo * 128;
  const int sw0 = ((((0 * 4 + lhi) ^ (llo & 7)) << 4)) + ro;
  const int sw1 = ((((1 * 4 + lhi) ^ (llo & 7)) << 4)) + ro;

  const f32x4 fzero = {0.f, 0.f, 0.f, 0.f};
  f32x4 o[4];
#pragma unroll
  for (int jd = 0; jd < 4; ++jd) o[jd] = fzero;
  float mrow = -1e30f, lsum = 0.f;

  auto issue = [&](int t) {
    gload16(kSrc + (size_t)t * KVB * HD, (char*)Kls[t & 3] + ldsOff);
    gload16(vSrc + t * KVB,              (char*)Vls[t & 3] + ldsOff);
  };

  auto compute = [&](int t) {
    const char* Kt = (const char*)Kls[t & 3];
    const char* Vt = (const char*)Vls[t & 3];

    // ---- S = K @ Q^T : D[kv,q] ----
    f32x4 s[4];
#pragma unroll
    for (int j = 0; j < 4; ++j) s[j] = fzero;
    __builtin_amdgcn_s_setprio(1);
#pragma unroll
    for (int j = 0; j < 4; ++j) {
      bf16x8 k0 = *(const bf16x8*)(Kt + sw0 + j * 2048);
      bf16x8 k1 = *(const bf16x8*)(Kt + sw1 + j * 2048);
      s[j] = __builtin_amdgcn_mfma_f32_16x16x32_bf16(k0, qf[0], s[j], 0, 0, 0);
      s[j] = __builtin_amdgcn_mfma_f32_16x16x32_bf16(k1, qf[1], s[j], 0, 0, 0);
    }
    __builtin_amdgcn_s_setprio(0);

    // ---- online softmax (exp2 domain; stats per q-col = llo) ----
    float tmax = -1e30f;
#pragma unroll
    for (int j = 0; j < 4; ++j) {
      const float a = fmaxf(s[j][0], s[j][1]), b = fmaxf(s[j][2], s[j][3]);
      tmax = fmaxf(tmax, fmaxf(a, b));
    }
    tmax = fmaxf(tmax, __shfl_xor(tmax, 16));
    tmax = fmaxf(tmax, __shfl_xor(tmax, 32));
    const float mnew  = fmaxf(mrow, tmax);
    const float alpha = exp2f(mrow - mnew);
    float tsum = 0.f;
    u32 dwp[4][2];
#pragma unroll
    for (int j = 0; j < 4; ++j) {
      const float p0 = exp2f(s[j][0] - mnew), p1 = exp2f(s[j][1] - mnew);
      const float p2 = exp2f(s[j][2] - mnew), p3 = exp2f(s[j][3] - mnew);
      tsum += (p0 + p1) + (p2 + p3);
      dwp[j][0] = cvtpk(p0, p1);
      dwp[j][1] = cvtpk(p2, p3);
    }
    tsum += __shfl_xor(tsum, 16);
    tsum += __shfl_xor(tsum, 32);
    lsum = lsum * alpha + tsum;
    mrow = mnew;

    // ---- redistribute P -> A-fragment layout (in-register) ----
    const int l0 = llo + ((lhi & 1) << 5);
    const int l1 = l0 + 16;
    const bool hi = (lhi & 2) != 0;
    bf16x8 pf[2];
#pragma unroll
    for (int kk = 0; kk < 2; ++kk) {
      const u32 a0 = __shfl(dwp[kk * 2][0], l0),     a1 = __shfl(dwp[kk * 2][1], l0);
      const u32 b0 = __shfl(dwp[kk * 2 + 1][0], l0), b1 = __shfl(dwp[kk * 2 + 1][1], l0);
      const u32 c0 = __shfl(dwp[kk * 2][0], l1),     c1 = __shfl(dwp[kk * 2][1], l1);
      const u32 d0 = __shfl(dwp[kk * 2 + 1][0], l1), d1 = __shfl(dwp[kk * 2 + 1][1], l1);
      union { u32 u[4]; bf16x8 v; } P;
      P.u[0] = hi ? b0 : a0;  P.u[1] = hi ? b1 : a1;
      P.u[2] = hi ? d0 : c0;  P.u[3] = hi ? d1 : c1;
      pf[kk] = P.v;
    }

    // ---- rescale O (factor for q-row lhi*4+r held by lane lhi*4+r) ----
#pragma unroll
    for (int r = 0; r < 4; ++r) {
      const float f = __shfl(alpha, lhi * 4 + r);
#pragma unroll
      for (int jd = 0; jd < 4; ++jd) o[jd][r] *= f;
    }

    // ---- O += P @ V : D[q,d] ----
    __builtin_amdgcn_s_setprio(1);
#pragma unroll
    for (int jd = 0; jd < 4; ++jd) {
      bf16x8 v0 = *(const bf16x8*)(Vt + sw0 + jd * 2048);
      bf16x8 v1 = *(const bf16x8*)(Vt + sw1 + jd * 2048);
      o[jd] = __builtin_amdgcn_mfma_f32_16x16x32_bf16(pf[0], v0, o[jd], 0, 0, 0);
      o[jd] = __builtin_amdgcn_mfma_f32_16x16x32_bf16(pf[1], v1, o[jd], 0, 0, 0);
    }
    __builtin_amdgcn_s_setprio(0);
  };

  // ---- prologue: prefetch tiles 0..2 (6 outstanding VMEM ops/thread) ----
  issue(0); issue(1); issue(2);

  // ---- main loop: counted vmcnt, loads stay in flight across barriers ----
#define BAR() do { asm volatile("" ::: "memory"); \
                   __builtin_amdgcn_s_barrier();  \
                   asm volatile("" ::: "memory"); } while (0)
  for (int t = 0; t < NT - 3; ++t) {
    issue(t + 3);                                   // 8 outstanding
    asm volatile("s_waitcnt vmcnt(6)" ::: "memory"); // tile t landed
    BAR();
    compute(t);
    BAR();                                          // buf (t+4)&3 free for reuse
  }
  asm volatile("s_waitcnt vmcnt(4)" ::: "memory");
  BAR(); compute(NT - 3); BAR();
  asm volatile("s_waitcnt vmcnt(2)" ::: "memory");
  BAR(); compute(NT - 2); BAR();
  asm volatile("s_waitcnt vmcnt(0)" ::: "memory");
  BAR(); compute(NT - 1);
#undef BAR

  // ---- finalize: /= lsum, write [B,S,H,d] bf16 ----
  const float li = 1.0f / lsum;
  const int b = bh >> 4, h = bh & 15;
#pragma unroll
  for (int r = 0; r < 4; ++r) {
    const float f = __shfl(li, lhi * 4 + r);
    const int q = q0 + wave * 16 + lhi * 4 + r;
    u16* dst = Obf + ((size_t)(b * S_ + q) * NH + h) * HD;
#pragma unroll
    for (int jd = 0; jd < 4; ++jd)
      dst[jd * 16 + llo] = f2bf(o[jd][r] * f);
  }
}

extern "C" void kernel_launch(void* const* d_in, const int* in_sizes, int n_in,
                              void* d_out, int out_size, void* d_ws, size_t ws_size,
                              hipStream_t stream) {
  const float* x     = (const float*)d_in[0];
  const float* qkv_w = (const float*)d_in[1];
  const float* qkv_b = (const float*)d_in[2];
  const float* o_w   = (const float*)d_in[3];
  const float* o_b   = (const float*)d_in[4];
  float* out = (float*)d_out;

  char* ws = (char*)d_ws;
  u16* xbf  = (u16*)(ws);                     // 8 MB; later aliased as attn output
  u16* wqkv = (u16*)(ws + (8u  << 20));       // 6 MB
  u16* wo   = (u16*)(ws + (14u << 20));       // 2 MB
  u16* Qb   = (u16*)(ws + (16u << 20));       // 8 MB  [B,H,S,d]
  u16* Kb   = (u16*)(ws + (24u << 20));       // 8 MB  [B,H,S,d]
  u16* VbT  = (u16*)(ws + (32u << 20));       // 8 MB  [B,H,d,S]
  u16* atnb = xbf;                            // [B,S,H,d] bf16 (x_bf dead by then)

  cast4<<<4096, 256, 0, stream>>>(x,     xbf,  1048576);
  cast4<<<3072, 256, 0, stream>>>(qkv_w, wqkv,  786432);
  cast4<<<1024, 256, 0, stream>>>(o_w,   wo,    262144);

  gemm_bt<0><<<dim3(N3 / 128, MROWS / 128), 256, 0, stream>>>(
      xbf, wqkv, qkv_b, nullptr, Qb, Kb, VbT, MROWS, N3, DIN);

  attn_fwd<<<dim3(S_ / QBLK, B_ * NH), 512, 0, stream>>>(Qb, Kb, VbT, atnb);

  gemm_bt<1><<<dim3(EMB / 128, MROWS / 128), 256, 0, stream>>>(
      atnb, wo, o_b, out, nullptr, nullptr, nullptr, MROWS, EMB, EMB);
}

// Round 5
// 161.064 us; speedup vs baseline: 1.0150x; 1.0150x over previous
//
#include <hip/hip_runtime.h>
#include <hip/hip_bf16.h>

#define B_    2
#define S_    2048
#define DIN   1024
#define EMB   1024
#define NH    16
#define HD    64
#define N3    3072
#define MROWS 4096   // B_*S_
#define KVB   64
#define QBLK  128
#define NT    (S_ / KVB)   // 32 kv tiles

typedef short bf16x8 __attribute__((ext_vector_type(8)));
typedef float f32x4  __attribute__((ext_vector_type(4)));
typedef float f32x16 __attribute__((ext_vector_type(16)));
typedef unsigned short u16;
typedef u16 u16x8 __attribute__((ext_vector_type(8)));
typedef u16 u16x4 __attribute__((ext_vector_type(4)));
typedef unsigned int u32;

__device__ __forceinline__ u16 f2bf(float f) {
  union { float f; unsigned u; } x; x.f = f;
  unsigned r = x.u + 0x7fffu + ((x.u >> 16) & 1u);
  return (u16)(r >> 16);
}

__device__ __forceinline__ u32 cvtpk(float lo, float hi) {
  u32 r;
  asm("v_cvt_pk_bf16_f32 %0, %1, %2" : "=v"(r) : "v"(lo), "v"(hi));
  return r;
}

__device__ __forceinline__ void gload16(const void* g, void* l) {
  __builtin_amdgcn_global_load_lds(
      (const __attribute__((address_space(1))) unsigned int*)g,
      (__attribute__((address_space(3))) unsigned int*)l, 16, 0, 0);
}

__global__ void cast4(const float* __restrict__ in, u16* __restrict__ out, int n4) {
  const int i = blockIdx.x * 256 + threadIdx.x;
  if (i < n4) {
    const float4 v = ((const float4*)in)[i];
    u16x4 o;
    o[0] = f2bf(v.x); o[1] = f2bf(v.y); o[2] = f2bf(v.z); o[3] = f2bf(v.w);
    ((u16x4*)out)[i] = o;
  }
}

// C[m,n] = sum_k A[m,k] * W[n,k] + bias[n]; A:[M][K] bf16, W:[N][K] bf16.
// EPI==0: scatter Q,K -> [B,H,S,d] bf16 (Q scaled by 0.125*log2e), V -> V^T [B,H,d,S].
// EPI==1: f32 out.
template<int EPI>
__global__ __launch_bounds__(256)
void gemm_bt(const u16* __restrict__ A, const u16* __restrict__ W,
             const float* __restrict__ bias, float* __restrict__ Cf,
             u16* __restrict__ Qb, u16* __restrict__ Kb, u16* __restrict__ VbT,
             int M, int N, int K) {
  __shared__ u16 Als[128 * 32];
  __shared__ u16 Bls[128 * 32];
  const int tid  = threadIdx.x;
  const int wave = tid >> 6, lane = tid & 63;
  const int lhi  = lane >> 4, llo = lane & 15;
  const int wr   = wave >> 1, wc = wave & 1;
  const int m0   = blockIdx.y * 128, n0 = blockIdx.x * 128;

  const f32x4 fzero = {0.f, 0.f, 0.f, 0.f};
  f32x4 acc[4][4];
#pragma unroll
  for (int m = 0; m < 4; ++m)
#pragma unroll
    for (int n = 0; n < 4; ++n) acc[m][n] = fzero;

  for (int k0 = 0; k0 < K; k0 += 32) {
#pragma unroll
    for (int i = 0; i < 2; ++i) {
      const int e   = (tid + i * 256) * 8;   // element index in [128][32] tile
      const int row = e >> 5, col = e & 31;
      gload16(A + (size_t)(m0 + row) * K + k0 + col, (char*)Als + wave * 1024 + i * 4096);
      gload16(W + (size_t)(n0 + row) * K + k0 + col, (char*)Bls + wave * 1024 + i * 4096);
    }
    __syncthreads();
    bf16x8 af[4], bfr[4];
#pragma unroll
    for (int m = 0; m < 4; ++m) af[m]  = *(const bf16x8*)&Als[(wr * 64 + m * 16 + llo) * 32 + lhi * 8];
#pragma unroll
    for (int n = 0; n < 4; ++n) bfr[n] = *(const bf16x8*)&Bls[(wc * 64 + n * 16 + llo) * 32 + lhi * 8];
#pragma unroll
    for (int m = 0; m < 4; ++m)
#pragma unroll
      for (int n = 0; n < 4; ++n)
        acc[m][n] = __builtin_amdgcn_mfma_f32_16x16x32_bf16(af[m], bfr[n], acc[m][n], 0, 0, 0);
    __syncthreads();
  }

#pragma unroll
  for (int n = 0; n < 4; ++n) {
    const int colb = n0 + wc * 64 + n * 16;  // 16-aligned; never crosses a 64-col section
    const int gcol = colb + llo;
    const float bv = bias[gcol];
    if (EPI == 0) {
      const int h   = colb / 192;
      const int rr  = colb - h * 192;
      const int sec = rr >> 6;               // 0:Q 1:K 2:V
      const int d   = (rr & 63) + llo;
#pragma unroll
      for (int m = 0; m < 4; ++m) {
        const int rowb = m0 + wr * 64 + m * 16 + lhi * 4;
        const int b = rowb >> 11, s0 = rowb & 2047;
        if (sec == 2) {
          u16x4 vv;
#pragma unroll
          for (int r = 0; r < 4; ++r) vv[r] = f2bf(acc[m][n][r] + bv);
          *(u16x4*)&VbT[((size_t)(b * NH + h) * HD + d) * S_ + s0] = vv;
        } else {
          u16* dst = (sec == 0) ? Qb : Kb;
          const float scl = (sec == 0) ? 0.18033688f : 1.0f;  // 0.125*log2(e) for Q
#pragma unroll
          for (int r = 0; r < 4; ++r)
            dst[(((size_t)(b * NH + h) * S_ + s0 + r) << 6) + d] = f2bf((acc[m][n][r] + bv) * scl);
        }
      }
    } else {
#pragma unroll
      for (int m = 0; m < 4; ++m) {
        const int rowb = m0 + wr * 64 + m * 16 + lhi * 4;
#pragma unroll
        for (int r = 0; r < 4; ++r)
          Cf[(size_t)(rowb + r) * N + gcol] = acc[m][n][r] + bv;
      }
    }
  }
}

// Flash attention fwd, 32x32x16-MFMA: grid (S/QBLK, B*NH), 256 threads = 4 waves,
// 32 q-rows/wave. Swapped QK^T (D[kv,q]) with PERMUTED K-row reads
// (g(q)=16(q>>4)+8((q>>2)&1)+(q&3)+4((q>>3)&1)) so that s[r] holds
// kv = 16*(r>>3)+8*hi+(r&7): cvt_pk pairs (s[2j],s[2j+1]) are then directly the
// PV A-fragment dwords in order -- zero cross-lane P movement. Softmax pair
// reduce via __shfl_xor(.,32); per-row alpha/lsum broadcast via per-wave LDS.
// Quad-buffered K/V^T tiles via global_load_lds (inverse-swizzled source),
// counted vmcnt, raw s_barrier.
__global__ __launch_bounds__(256)
void attn_fwd(const u16* __restrict__ Qb, const u16* __restrict__ Kb,
              const u16* __restrict__ VbT, u16* __restrict__ Obf) {
  __shared__ __align__(16) u16 Kls[4][KVB * HD];   // 4 x 8KB  [kv=64][d=64]
  __shared__ __align__(16) u16 Vls[4][HD * KVB];   // 4 x 8KB  [d=64][kv=64]
  __shared__ __align__(16) float sBc[4][32];       // per-wave broadcast scratch
  const int tid  = threadIdx.x;
  const int wave = tid >> 6, lane = tid & 63;
  const int q    = lane & 31, hi = lane >> 5;
  const int bh   = blockIdx.y;
  const int q0   = blockIdx.x * QBLK;
  const size_t base  = (size_t)bh * S_ * HD;   // Q, K
  const size_t basev = (size_t)bh * HD * S_;   // V^T

  // Q fragments: wave handles q-rows q0 + wave*32 + (0..31); B-frag per 16-d chunk
  const int qrow = q0 + wave * 32 + q;
  bf16x8 qf[4];
#pragma unroll
  for (int c = 0; c < 4; ++c)
    qf[c] = *(const bf16x8*)&Qb[base + (size_t)qrow * HD + c * 16 + hi * 8];

  // staging: 256 threads x 16B x 2 passes per 8KB tile; LDS dest linear,
  // global source inverse-swizzled so swizzled reads return plain (row,slot)
  const int srow = tid >> 3;                       // 0..31 (+32 on pass 1)
  const int xs   = (tid & 7) ^ (srow & 7);
  const u16* kSrc = Kb  + base  + (size_t)srow * HD + xs * 8;
  const u16* vSrc = VbT + basev + (size_t)srow * S_ + xs * 8;
  const int ldsW = wave * 1024;

  // K-row read permutation (involution): kv sits at reg/lane-half positions that
  // make cvt_pk dwords the PV A-fragment directly.
  const int gq = 16 * (q >> 4) + 8 * ((q >> 2) & 1) + (q & 3) + 4 * ((q >> 3) & 1);

  // swizzled ds-read byte offsets: row*128 + ((slot ^ (row&7))<<4), slot = c*2+hi
  int offK[2][4], offV[2][4];
#pragma unroll
  for (int b = 0; b < 2; ++b)
#pragma unroll
    for (int c = 0; c < 4; ++c) {
      offK[b][c] = (b * 32 + gq) * 128 + (((c * 2 + hi) ^ (gq & 7)) << 4);
      offV[b][c] = (b * 32 + q)  * 128 + (((c * 2 + hi) ^ (q  & 7)) << 4);
    }

  f32x16 o0, o1;
#pragma unroll
  for (int r = 0; r < 16; ++r) { o0[r] = 0.f; o1[r] = 0.f; }
  float m_run = -1e30f, lsum = 0.f;

  auto issue = [&](int t) {
#pragma unroll
    for (int p = 0; p < 2; ++p) {
      gload16(kSrc + (size_t)t * KVB * HD + (size_t)p * 32 * HD,
              (char*)Kls[t & 3] + p * 4096 + ldsW);
      gload16(vSrc + t * KVB + (size_t)p * 32 * S_,
              (char*)Vls[t & 3] + p * 4096 + ldsW);
    }
  };

  auto compute = [&](int t) {
    const char* Kt = (const char*)Kls[t & 3];
    const char* Vt = (const char*)Vls[t & 3];

    // ---- S = K @ Q^T : D[kv-permuted, q] ----
    f32x16 s0, s1;
#pragma unroll
    for (int r = 0; r < 16; ++r) { s0[r] = 0.f; s1[r] = 0.f; }
    __builtin_amdgcn_s_setprio(1);
#pragma unroll
    for (int c = 0; c < 4; ++c) {
      bf16x8 k0 = *(const bf16x8*)(Kt + offK[0][c]);
      bf16x8 k1 = *(const bf16x8*)(Kt + offK[1][c]);
      s0 = __builtin_amdgcn_mfma_f32_32x32x16_bf16(k0, qf[c], s0, 0, 0, 0);
      s1 = __builtin_amdgcn_mfma_f32_32x32x16_bf16(k1, qf[c], s1, 0, 0, 0);
    }
    __builtin_amdgcn_s_setprio(0);

    // ---- tile max (per q-col): 31 in-lane fmax + cross-pair shfl ----
    float pm = fmaxf(s0[0], s1[0]);
#pragma unroll
    for (int r = 1; r < 16; ++r) pm = fmaxf(pm, fmaxf(s0[r], s1[r]));
    pm = fmaxf(pm, __shfl_xor(pm, 32));

    const float mnew  = fmaxf(m_run, pm);
    const float alpha = exp2f(m_run - mnew);   // first tile: exp2(-huge)=0

    // ---- broadcast alpha per q-row, rescale O ----
    sBc[wave][q] = alpha;                      // lanes q and q+32: same value
    asm volatile("s_waitcnt lgkmcnt(0)" ::: "memory");
    f32x4 av[4];
#pragma unroll
    for (int g = 0; g < 4; ++g) av[g] = *(const f32x4*)&sBc[wave][hi * 4 + g * 8];
#pragma unroll
    for (int r = 0; r < 16; ++r) {
      const float f = av[r >> 2][r & 3];       // alpha for q-row crow(r,hi)
      o0[r] *= f; o1[r] *= f;
    }

    // ---- P = exp2(S - mnew), pack bf16 pairs (= PV A-frag dwords), row-sum ----
    float ts = 0.f;
    u32 dw0[8], dw1[8];
#pragma unroll
    for (int j = 0; j < 8; ++j) {
      const float a0 = exp2f(s0[2 * j] - mnew), a1 = exp2f(s0[2 * j + 1] - mnew);
      const float b0 = exp2f(s1[2 * j] - mnew), b1 = exp2f(s1[2 * j + 1] - mnew);
      ts += (a0 + a1) + (b0 + b1);
      dw0[j] = cvtpk(a0, a1);
      dw1[j] = cvtpk(b0, b1);
    }
    ts += __shfl_xor(ts, 32);
    lsum = lsum * alpha + ts;
    m_run = mnew;

    // ---- O += P @ V : D[q,d]; chunk c kv-frag = dw[4c..4c+3] directly ----
    __builtin_amdgcn_s_setprio(1);
#pragma unroll
    for (int c = 0; c < 4; ++c) {
      union { u32 u[4]; bf16x8 v; } P;
      if (c == 0)      { P.u[0] = dw0[0]; P.u[1] = dw0[1]; P.u[2] = dw0[2]; P.u[3] = dw0[3]; }
      else if (c == 1) { P.u[0] = dw0[4]; P.u[1] = dw0[5]; P.u[2] = dw0[6]; P.u[3] = dw0[7]; }
      else if (c == 2) { P.u[0] = dw1[0]; P.u[1] = dw1[1]; P.u[2] = dw1[2]; P.u[3] = dw1[3]; }
      else             { P.u[0] = dw1[4]; P.u[1] = dw1[5]; P.u[2] = dw1[6]; P.u[3] = dw1[7]; }
      bf16x8 v0 = *(const bf16x8*)(Vt + offV[0][c]);
      bf16x8 v1 = *(const bf16x8*)(Vt + offV[1][c]);
      o0 = __builtin_amdgcn_mfma_f32_32x32x16_bf16(P.v, v0, o0, 0, 0, 0);
      o1 = __builtin_amdgcn_mfma_f32_32x32x16_bf16(P.v, v1, o1, 0, 0, 0);
    }
    __builtin_amdgcn_s_setprio(0);
  };

  // ---- prologue: prefetch tiles 0..2 (12 outstanding gloads) ----
  issue(0); issue(1); issue(2);

#define BAR() do { asm volatile("" ::: "memory"); \
                   __builtin_amdgcn_s_barrier();  \
                   asm volatile("" ::: "memory"); } while (0)
  for (int t = 0; t < NT - 3; ++t) {
    issue(t + 3);                                    // 16 outstanding
    asm volatile("s_waitcnt vmcnt(12)" ::: "memory"); // tile t landed
    BAR();
    compute(t);
    BAR();                                           // buf (t+4)&3 free for reuse
  }
  asm volatile("s_waitcnt vmcnt(8)" ::: "memory");
  BAR(); compute(NT - 3); BAR();
  asm volatile("s_waitcnt vmcnt(4)" ::: "memory");
  BAR(); compute(NT - 2); BAR();
  asm volatile("s_waitcnt vmcnt(0)" ::: "memory");
  BAR(); compute(NT - 1);
#undef BAR

  // ---- finalize: /= lsum (broadcast per q-row via LDS), write [B,S,H,d] ----
  const float li = 1.0f / lsum;
  sBc[wave][q] = li;
  asm volatile("s_waitcnt lgkmcnt(0)" ::: "memory");
  f32x4 lv[4];
#pragma unroll
  for (int g = 0; g < 4; ++g) lv[g] = *(const f32x4*)&sBc[wave][hi * 4 + g * 8];
  const int b = bh >> 4, h = bh & 15;
#pragma unroll
  for (int r = 0; r < 16; ++r) {
    const int qg = q0 + wave * 32 + (r & 3) + 8 * (r >> 2) + 4 * hi;
    const float f = lv[r >> 2][r & 3];
    u16* dst = Obf + ((size_t)(b * S_ + qg) * NH + h) * HD;
    dst[q]      = f2bf(o0[r] * f);
    dst[32 + q] = f2bf(o1[r] * f);
  }
}

extern "C" void kernel_launch(void* const* d_in, const int* in_sizes, int n_in,
                              void* d_out, int out_size, void* d_ws, size_t ws_size,
                              hipStream_t stream) {
  const float* x     = (const float*)d_in[0];
  const float* qkv_w = (const float*)d_in[1];
  const float* qkv_b = (const float*)d_in[2];
  const float* o_w   = (const float*)d_in[3];
  const float* o_b   = (const float*)d_in[4];
  float* out = (float*)d_out;

  char* ws = (char*)d_ws;
  u16* xbf  = (u16*)(ws);                     // 8 MB; later aliased as attn output
  u16* wqkv = (u16*)(ws + (8u  << 20));       // 6 MB
  u16* wo   = (u16*)(ws + (14u << 20));       // 2 MB
  u16* Qb   = (u16*)(ws + (16u << 20));       // 8 MB  [B,H,S,d]
  u16* Kb   = (u16*)(ws + (24u << 20));       // 8 MB  [B,H,S,d]
  u16* VbT  = (u16*)(ws + (32u << 20));       // 8 MB  [B,H,d,S]
  u16* atnb = xbf;                            // [B,S,H,d] bf16 (x_bf dead by then)

  cast4<<<4096, 256, 0, stream>>>(x,     xbf,  1048576);
  cast4<<<3072, 256, 0, stream>>>(qkv_w, wqkv,  786432);
  cast4<<<1024, 256, 0, stream>>>(o_w,   wo,    262144);

  gemm_bt<0><<<dim3(N3 / 128, MROWS / 128), 256, 0, stream>>>(
      xbf, wqkv, qkv_b, nullptr, Qb, Kb, VbT, MROWS, N3, DIN);

  attn_fwd<<<dim3(S_ / QBLK, B_ * NH), 256, 0, stream>>>(Qb, Kb, VbT, atnb);

  gemm_bt<1><<<dim3(EMB / 128, MROWS / 128), 256, 0, stream>>>(
      atnb, wo, o_b, out, nullptr, nullptr, nullptr, MROWS, EMB, EMB);
}

// Round 6
// 151.738 us; speedup vs baseline: 1.0774x; 1.0615x over previous
//
#include <hip/hip_runtime.h>
#include <hip/hip_bf16.h>

#define B_    2
#define S_    2048
#define DIN   1024
#define EMB   1024
#define NH    16
#define HD    64
#define N3    3072
#define MROWS 4096   // B_*S_
#define KVB   64
#define QBLK  128
#define NT    (S_ / KVB)   // 32 kv tiles

typedef short bf16x8 __attribute__((ext_vector_type(8)));
typedef float f32x4  __attribute__((ext_vector_type(4)));
typedef float f32x16 __attribute__((ext_vector_type(16)));
typedef unsigned short u16;
typedef u16 u16x8 __attribute__((ext_vector_type(8)));
typedef u16 u16x4 __attribute__((ext_vector_type(4)));
typedef unsigned int u32;

__device__ __forceinline__ u16 f2bf(float f) {
  union { float f; unsigned u; } x; x.f = f;
  unsigned r = x.u + 0x7fffu + ((x.u >> 16) & 1u);
  return (u16)(r >> 16);
}

__device__ __forceinline__ u32 cvtpk(float lo, float hi) {
  u32 r;
  asm("v_cvt_pk_bf16_f32 %0, %1, %2" : "=v"(r) : "v"(lo), "v"(hi));
  return r;
}

__device__ __forceinline__ void gload16(const void* g, void* l) {
  __builtin_amdgcn_global_load_lds(
      (const __attribute__((address_space(1))) unsigned int*)g,
      (__attribute__((address_space(3))) unsigned int*)l, 16, 0, 0);
}

__global__ void cast4(const float* __restrict__ in, u16* __restrict__ out, int n4) {
  const int i = blockIdx.x * 256 + threadIdx.x;
  if (i < n4) {
    const float4 v = ((const float4*)in)[i];
    u16x4 o;
    o[0] = f2bf(v.x); o[1] = f2bf(v.y); o[2] = f2bf(v.z); o[3] = f2bf(v.w);
    ((u16x4*)out)[i] = o;
  }
}

// C[m,n] = sum_k A[m,k] * W[n,k] + bias[n]; A:[M][K] bf16, W:[N][K] bf16.
// EPI==0: scatter Q,K -> [B,H,S,d] bf16 (Q scaled by 0.125*log2e), V -> V^T [B,H,d,S].
// EPI==1: f32 out.
template<int EPI>
__global__ __launch_bounds__(256)
void gemm_bt(const u16* __restrict__ A, const u16* __restrict__ W,
             const float* __restrict__ bias, float* __restrict__ Cf,
             u16* __restrict__ Qb, u16* __restrict__ Kb, u16* __restrict__ VbT,
             int M, int N, int K) {
  __shared__ u16 Als[128 * 32];
  __shared__ u16 Bls[128 * 32];
  const int tid  = threadIdx.x;
  const int wave = tid >> 6, lane = tid & 63;
  const int lhi  = lane >> 4, llo = lane & 15;
  const int wr   = wave >> 1, wc = wave & 1;
  const int m0   = blockIdx.y * 128, n0 = blockIdx.x * 128;

  const f32x4 fzero = {0.f, 0.f, 0.f, 0.f};
  f32x4 acc[4][4];
#pragma unroll
  for (int m = 0; m < 4; ++m)
#pragma unroll
    for (int n = 0; n < 4; ++n) acc[m][n] = fzero;

  for (int k0 = 0; k0 < K; k0 += 32) {
#pragma unroll
    for (int i = 0; i < 2; ++i) {
      const int e   = (tid + i * 256) * 8;   // element index in [128][32] tile
      const int row = e >> 5, col = e & 31;
      gload16(A + (size_t)(m0 + row) * K + k0 + col, (char*)Als + wave * 1024 + i * 4096);
      gload16(W + (size_t)(n0 + row) * K + k0 + col, (char*)Bls + wave * 1024 + i * 4096);
    }
    __syncthreads();
    bf16x8 af[4], bfr[4];
#pragma unroll
    for (int m = 0; m < 4; ++m) af[m]  = *(const bf16x8*)&Als[(wr * 64 + m * 16 + llo) * 32 + lhi * 8];
#pragma unroll
    for (int n = 0; n < 4; ++n) bfr[n] = *(const bf16x8*)&Bls[(wc * 64 + n * 16 + llo) * 32 + lhi * 8];
#pragma unroll
    for (int m = 0; m < 4; ++m)
#pragma unroll
      for (int n = 0; n < 4; ++n)
        acc[m][n] = __builtin_amdgcn_mfma_f32_16x16x32_bf16(af[m], bfr[n], acc[m][n], 0, 0, 0);
    __syncthreads();
  }

#pragma unroll
  for (int n = 0; n < 4; ++n) {
    const int colb = n0 + wc * 64 + n * 16;  // 16-aligned; never crosses a 64-col section
    const int gcol = colb + llo;
    const float bv = bias[gcol];
    if (EPI == 0) {
      const int h   = colb / 192;
      const int rr  = colb - h * 192;
      const int sec = rr >> 6;               // 0:Q 1:K 2:V
      const int d   = (rr & 63) + llo;
#pragma unroll
      for (int m = 0; m < 4; ++m) {
        const int rowb = m0 + wr * 64 + m * 16 + lhi * 4;
        const int b = rowb >> 11, s0 = rowb & 2047;
        if (sec == 2) {
          u16x4 vv;
#pragma unroll
          for (int r = 0; r < 4; ++r) vv[r] = f2bf(acc[m][n][r] + bv);
          *(u16x4*)&VbT[((size_t)(b * NH + h) * HD + d) * S_ + s0] = vv;
        } else {
          u16* dst = (sec == 0) ? Qb : Kb;
          const float scl = (sec == 0) ? 0.18033688f : 1.0f;  // 0.125*log2(e) for Q
#pragma unroll
          for (int r = 0; r < 4; ++r)
            dst[(((size_t)(b * NH + h) * S_ + s0 + r) << 6) + d] = f2bf((acc[m][n][r] + bv) * scl);
        }
      }
    } else {
#pragma unroll
      for (int m = 0; m < 4; ++m) {
        const int rowb = m0 + wr * 64 + m * 16 + lhi * 4;
#pragma unroll
        for (int r = 0; r < 4; ++r)
          Cf[(size_t)(rowb + r) * N + gcol] = acc[m][n][r] + bv;
      }
    }
  }
}

// Flash attention fwd, 32x32x16-MFMA: grid (S/QBLK, B*NH), 256 threads = 4 waves,
// 32 q-rows/wave. Swapped QK^T (D[kv,q]) with PERMUTED K-row reads so cvt_pk
// pairs are directly the PV A-fragment dwords (zero cross-lane P movement).
// TWO-TILE phases (ILP + half the barriers), defer-max (skip O-rescale unless
// running max grows >10 in log2 domain), tree reductions. Quad-buffered K/V^T
// via global_load_lds (inverse-swizzled source), counted vmcnt, raw s_barrier.
__global__ __launch_bounds__(256)
void attn_fwd(const u16* __restrict__ Qb, const u16* __restrict__ Kb,
              const u16* __restrict__ VbT, u16* __restrict__ Obf) {
  __shared__ __align__(16) u16 Kls[4][KVB * HD];   // 4 x 8KB  [kv=64][d=64]
  __shared__ __align__(16) u16 Vls[4][HD * KVB];   // 4 x 8KB  [d=64][kv=64]
  __shared__ __align__(16) float sBc[4][32];       // per-wave broadcast scratch
  const int tid  = threadIdx.x;
  const int wave = tid >> 6, lane = tid & 63;
  const int q    = lane & 31, hi = lane >> 5;
  const int bh   = blockIdx.y;
  const int q0   = blockIdx.x * QBLK;
  const size_t base  = (size_t)bh * S_ * HD;   // Q, K
  const size_t basev = (size_t)bh * HD * S_;   // V^T

  // Q fragments: wave handles q-rows q0 + wave*32 + (0..31); B-frag per 16-d chunk
  const int qrow = q0 + wave * 32 + q;
  bf16x8 qf[4];
#pragma unroll
  for (int c = 0; c < 4; ++c)
    qf[c] = *(const bf16x8*)&Qb[base + (size_t)qrow * HD + c * 16 + hi * 8];

  // staging: 256 threads x 16B x 2 passes per 8KB tile; LDS dest linear,
  // global source inverse-swizzled so swizzled reads return plain (row,slot)
  const int srow = tid >> 3;                       // 0..31 (+32 on pass 1)
  const int xs   = (tid & 7) ^ (srow & 7);
  const u16* kSrc = Kb  + base  + (size_t)srow * HD + xs * 8;
  const u16* vSrc = VbT + basev + (size_t)srow * S_ + xs * 8;
  const int ldsW = wave * 1024;

  // K-row read permutation (involution): kv sits at reg/lane-half positions that
  // make cvt_pk dwords the PV A-fragment directly.
  const int gq = 16 * (q >> 4) + 8 * ((q >> 2) & 1) + (q & 3) + 4 * ((q >> 3) & 1);

  // swizzled ds-read byte offsets: row*128 + ((slot ^ (row&7))<<4), slot = c*2+hi
  int offK[2][4], offV[2][4];
#pragma unroll
  for (int b = 0; b < 2; ++b)
#pragma unroll
    for (int c = 0; c < 4; ++c) {
      offK[b][c] = (b * 32 + gq) * 128 + (((c * 2 + hi) ^ (gq & 7)) << 4);
      offV[b][c] = (b * 32 + q)  * 128 + (((c * 2 + hi) ^ (q  & 7)) << 4);
    }

  f32x16 o0, o1;
#pragma unroll
  for (int r = 0; r < 16; ++r) { o0[r] = 0.f; o1[r] = 0.f; }
  float m_run = -1e30f, lsum = 0.f;

  auto issue = [&](int t) {
#pragma unroll
    for (int p = 0; p < 2; ++p) {
      gload16(kSrc + (size_t)t * KVB * HD + (size_t)p * 32 * HD,
              (char*)Kls[t & 3] + p * 4096 + ldsW);
      gload16(vSrc + t * KVB + (size_t)p * 32 * S_,
              (char*)Vls[t & 3] + p * 4096 + ldsW);
    }
  };

  auto compute = [&](int t) {
    const char* Kt = (const char*)Kls[t & 3];
    const char* Vt = (const char*)Vls[t & 3];

    // ---- S = K @ Q^T : D[kv-permuted, q] ----
    f32x16 s0, s1;
#pragma unroll
    for (int r = 0; r < 16; ++r) { s0[r] = 0.f; s1[r] = 0.f; }
    __builtin_amdgcn_s_setprio(1);
#pragma unroll
    for (int c = 0; c < 4; ++c) {
      bf16x8 k0 = *(const bf16x8*)(Kt + offK[0][c]);
      bf16x8 k1 = *(const bf16x8*)(Kt + offK[1][c]);
      s0 = __builtin_amdgcn_mfma_f32_32x32x16_bf16(k0, qf[c], s0, 0, 0, 0);
      s1 = __builtin_amdgcn_mfma_f32_32x32x16_bf16(k1, qf[c], s1, 0, 0, 0);
    }
    __builtin_amdgcn_s_setprio(0);

    // ---- tile max (per q-col): pairwise tree + cross-pair shfl ----
    float tm[16];
#pragma unroll
    for (int r = 0; r < 16; ++r) tm[r] = fmaxf(s0[r], s1[r]);
#pragma unroll
    for (int st = 8; st >= 1; st >>= 1)
#pragma unroll
      for (int i = 0; i < 16; ++i) if (i < st) tm[i] = fmaxf(tm[i], tm[i + st]);
    const float pm = fmaxf(tm[0], __shfl_xor(tm[0], 32));

    // ---- defer-max: rescale O only when max grew past threshold ----
    if (__any(pm > m_run + 10.0f)) {
      const float mnew  = fmaxf(m_run, pm);
      const float alpha = exp2f(m_run - mnew);   // first tile: 0
      sBc[wave][q] = alpha;                      // lanes q, q+32: same value
      asm volatile("s_waitcnt lgkmcnt(0)" ::: "memory");
      f32x4 av[4];
#pragma unroll
      for (int g = 0; g < 4; ++g) av[g] = *(const f32x4*)&sBc[wave][hi * 4 + g * 8];
#pragma unroll
      for (int r = 0; r < 16; ++r) {
        const float f = av[r >> 2][r & 3];       // alpha for q-row crow(r,hi)
        o0[r] *= f; o1[r] *= f;
      }
      lsum *= alpha;
      m_run = mnew;
    }

    // ---- P = exp2(S - m_run), pack bf16 pairs (= PV A-frag dwords), row-sum ----
    float t0 = 0.f, t1 = 0.f, t2 = 0.f, t3 = 0.f;
    u32 dw0[8], dw1[8];
#pragma unroll
    for (int j = 0; j < 8; ++j) {
      const float a0 = exp2f(s0[2 * j] - m_run), a1 = exp2f(s0[2 * j + 1] - m_run);
      const float b0 = exp2f(s1[2 * j] - m_run), b1 = exp2f(s1[2 * j + 1] - m_run);
      t0 += a0; t1 += a1; t2 += b0; t3 += b1;
      dw0[j] = cvtpk(a0, a1);
      dw1[j] = cvtpk(b0, b1);
    }
    float ts = (t0 + t1) + (t2 + t3);
    ts += __shfl_xor(ts, 32);
    lsum += ts;

    // ---- O += P @ V : D[q,d]; chunk c kv-frag = dw[4c..4c+3] directly ----
    __builtin_amdgcn_s_setprio(1);
#pragma unroll
    for (int c = 0; c < 4; ++c) {
      union { u32 u[4]; bf16x8 v; } P;
      if (c == 0)      { P.u[0] = dw0[0]; P.u[1] = dw0[1]; P.u[2] = dw0[2]; P.u[3] = dw0[3]; }
      else if (c == 1) { P.u[0] = dw0[4]; P.u[1] = dw0[5]; P.u[2] = dw0[6]; P.u[3] = dw0[7]; }
      else if (c == 2) { P.u[0] = dw1[0]; P.u[1] = dw1[1]; P.u[2] = dw1[2]; P.u[3] = dw1[3]; }
      else             { P.u[0] = dw1[4]; P.u[1] = dw1[5]; P.u[2] = dw1[6]; P.u[3] = dw1[7]; }
      bf16x8 v0 = *(const bf16x8*)(Vt + offV[0][c]);
      bf16x8 v1 = *(const bf16x8*)(Vt + offV[1][c]);
      o0 = __builtin_amdgcn_mfma_f32_32x32x16_bf16(P.v, v0, o0, 0, 0, 0);
      o1 = __builtin_amdgcn_mfma_f32_32x32x16_bf16(P.v, v1, o1, 0, 0, 0);
    }
    __builtin_amdgcn_s_setprio(0);
  };

  // ---- prologue: prefetch pair 0 (tiles 0,1) = 8 outstanding gloads ----
  issue(0); issue(1);

#define BAR() do { asm volatile("" ::: "memory"); \
                   __builtin_amdgcn_s_barrier();  \
                   asm volatile("" ::: "memory"); } while (0)
  // two-tile phases: pair p computes tiles 2p,2p+1; pair p+1 stays in flight
  for (int p = 0; p < NT / 2 - 1; ++p) {
    issue(2 * p + 2); issue(2 * p + 3);              // 16 outstanding
    asm volatile("s_waitcnt vmcnt(8)" ::: "memory"); // pair p landed
    BAR();
    compute(2 * p);
    compute(2 * p + 1);
    BAR();                                           // pair p bufs free for reuse
  }
  asm volatile("s_waitcnt vmcnt(0)" ::: "memory");
  BAR();
  compute(NT - 2);
  compute(NT - 1);
#undef BAR

  // ---- finalize: /= lsum (broadcast per q-row via LDS), write [B,S,H,d] ----
  const float li = 1.0f / lsum;
  sBc[wave][q] = li;
  asm volatile("s_waitcnt lgkmcnt(0)" ::: "memory");
  f32x4 lv[4];
#pragma unroll
  for (int g = 0; g < 4; ++g) lv[g] = *(const f32x4*)&sBc[wave][hi * 4 + g * 8];
  const int b = bh >> 4, h = bh & 15;
#pragma unroll
  for (int r = 0; r < 16; ++r) {
    const int qg = q0 + wave * 32 + (r & 3) + 8 * (r >> 2) + 4 * hi;
    const float f = lv[r >> 2][r & 3];
    u16* dst = Obf + ((size_t)(b * S_ + qg) * NH + h) * HD;
    dst[q]      = f2bf(o0[r] * f);
    dst[32 + q] = f2bf(o1[r] * f);
  }
}

extern "C" void kernel_launch(void* const* d_in, const int* in_sizes, int n_in,
                              void* d_out, int out_size, void* d_ws, size_t ws_size,
                              hipStream_t stream) {
  const float* x     = (const float*)d_in[0];
  const float* qkv_w = (const float*)d_in[1];
  const float* qkv_b = (const float*)d_in[2];
  const float* o_w   = (const float*)d_in[3];
  const float* o_b   = (const float*)d_in[4];
  float* out = (float*)d_out;

  char* ws = (char*)d_ws;
  u16* xbf  = (u16*)(ws);                     // 8 MB; later aliased as attn output
  u16* wqkv = (u16*)(ws + (8u  << 20));       // 6 MB
  u16* wo   = (u16*)(ws + (14u << 20));       // 2 MB
  u16* Qb   = (u16*)(ws + (16u << 20));       // 8 MB  [B,H,S,d]
  u16* Kb   = (u16*)(ws + (24u << 20));       // 8 MB  [B,H,S,d]
  u16* VbT  = (u16*)(ws + (32u << 20));       // 8 MB  [B,H,d,S]
  u16* atnb = xbf;                            // [B,S,H,d] bf16 (x_bf dead by then)

  cast4<<<4096, 256, 0, stream>>>(x,     xbf,  1048576);
  cast4<<<3072, 256, 0, stream>>>(qkv_w, wqkv,  786432);
  cast4<<<1024, 256, 0, stream>>>(o_w,   wo,    262144);

  gemm_bt<0><<<dim3(N3 / 128, MROWS / 128), 256, 0, stream>>>(
      xbf, wqkv, qkv_b, nullptr, Qb, Kb, VbT, MROWS, N3, DIN);

  attn_fwd<<<dim3(S_ / QBLK, B_ * NH), 256, 0, stream>>>(Qb, Kb, VbT, atnb);

  gemm_bt<1><<<dim3(EMB / 128, MROWS / 128), 256, 0, stream>>>(
      atnb, wo, o_b, out, nullptr, nullptr, nullptr, MROWS, EMB, EMB);
}